// Round 9
// baseline (306.617 us; speedup 1.0000x reference)
//
#include <hip/hip_runtime.h>

typedef __bf16 bf16;
typedef __bf16 bf16x4 __attribute__((ext_vector_type(4)));
typedef __bf16 bf16x8 __attribute__((ext_vector_type(8)));
typedef float f32x4 __attribute__((ext_vector_type(4)));

#define D_MODEL 1024
#define SEQ 2048
#define NB 2
#define LOG2E 1.4426950408889634f

// async global->LDS, 16B per lane; LDS dest = wave-uniform base + lane*16
__device__ __forceinline__ void glds16(const bf16* g, bf16* l) {
    __builtin_amdgcn_global_load_lds(
        (const __attribute__((address_space(1))) void*)g,
        (__attribute__((address_space(3))) void*)l, 16, 0, 0);
}

// ---------------- fused prep (weights W^T + bias concat) + norm1 ----------------
__device__ __forceinline__ void tile_tcvt(
    const float* __restrict__ src, int rows, int cols, bf16* __restrict__ dst,
    int bx, int by, bf16 (*t)[72])
{
    int tid = threadIdx.x;
    int k0 = by * 64, n0 = bx * 64;
    int r = tid >> 2, c = (tid & 3) * 16;
    const float4* s = (const float4*)(src + (size_t)(k0 + r) * cols + n0 + c);
#pragma unroll
    for (int q = 0; q < 4; ++q) {
        float4 v = s[q];
        t[c + q * 4 + 0][r] = (bf16)v.x;
        t[c + q * 4 + 1][r] = (bf16)v.y;
        t[c + q * 4 + 2][r] = (bf16)v.z;
        t[c + q * 4 + 3][r] = (bf16)v.w;
    }
    __syncthreads();
    bf16* d = dst + (size_t)(n0 + r) * rows + k0 + c;
    *(bf16x8*)(d)     = *(const bf16x8*)&t[r][c];
    *(bf16x8*)(d + 8) = *(const bf16x8*)&t[r][c + 8];
}

__device__ __forceinline__ void norm_row(
    const float* __restrict__ X, const float* __restrict__ alpha,
    const float* __restrict__ beta, bf16* __restrict__ Y, int row)
{
    int tid = threadIdx.x;
    float4 v = ((const float4*)(X + (size_t)row * D_MODEL))[tid];
    float s = v.x + v.y + v.z + v.w;
    float ss = v.x*v.x + v.y*v.y + v.z*v.z + v.w*v.w;
#pragma unroll
    for (int off = 1; off < 64; off <<= 1) {
        s  += __shfl_xor(s, off, 64);
        ss += __shfl_xor(ss, off, 64);
    }
    __shared__ float sd[8];
    int wave = tid >> 6, lane = tid & 63;
    if (lane == 0) { sd[wave] = s; sd[4 + wave] = ss; }
    __syncthreads();
    s  = sd[0] + sd[1] + sd[2] + sd[3];
    ss = sd[4] + sd[5] + sd[6] + sd[7];
    float mean = s * (1.0f / 1024.0f);
    float var  = (ss - s * mean) * (1.0f / 1023.0f);
    float rs = rsqrtf(var + 1e-6f);
    float4 a = ((const float4*)alpha)[tid];
    float4 bt = ((const float4*)beta)[tid];
    bf16x4 o;
    o[0] = (bf16)(a.x * (v.x - mean) * rs + bt.x);
    o[1] = (bf16)(a.y * (v.y - mean) * rs + bt.y);
    o[2] = (bf16)(a.z * (v.z - mean) * rs + bt.z);
    o[3] = (bf16)(a.w * (v.w - mean) * rs + bt.w);
    *(bf16x4*)(Y + (size_t)row * D_MODEL + tid * 4) = o;
}

__global__ __launch_bounds__(256) void prep_norm_kernel(
    const float* __restrict__ x, const float* __restrict__ alpha1,
    const float* __restrict__ beta1, bf16* __restrict__ xn,
    const float* __restrict__ Wq, const float* __restrict__ Wk,
    const float* __restrict__ Wv, const float* __restrict__ Wo,
    const float* __restrict__ W1, const float* __restrict__ W2,
    const float* __restrict__ bq, const float* __restrict__ bk,
    const float* __restrict__ bv,
    bf16* __restrict__ Wqkv_t, bf16* __restrict__ Wo_t,
    bf16* __restrict__ W1_t, bf16* __restrict__ W2_t,
    float* __restrict__ b_qkv)
{
    __shared__ bf16 t[64][72];
    int id = blockIdx.x;
    if (id < 4096) {
        norm_row(x, alpha1, beta1, xn, id);
        return;
    }
    id -= 4096;
    if (id < 1024) {
        int which = id >> 8, tile = id & 255;
        const float* src = which == 0 ? Wq : which == 1 ? Wk : which == 2 ? Wv : Wo;
        bf16* dst = which == 3 ? Wo_t : Wqkv_t + (size_t)which * 1024 * 1024;
        tile_tcvt(src, 1024, 1024, dst, tile & 15, tile >> 4, t);
    } else if (id < 1152) {
        int tile = id - 1024;
        tile_tcvt(W1, 1024, 512, W1_t, tile & 7, tile >> 3, t);
    } else if (id < 1280) {
        int tile = id - 1152;
        tile_tcvt(W2, 512, 1024, W2_t, tile & 15, tile >> 4, t);
    } else {
        int i = (id - 1280) * 256 + threadIdx.x;
        float v;
        if (i < 1024) v = bq[i];
        else if (i < 2048) v = bk[i - 1024];
        else v = bv[i - 2048];
        b_qkv[i] = v;
    }
}

// ---------------- LayerNorm standalone (norm2) ----------------
__global__ __launch_bounds__(256) void norm_kernel(
    const float* __restrict__ X, const float* __restrict__ alpha,
    const float* __restrict__ beta, bf16* __restrict__ Y)
{
    norm_row(X, alpha, beta, Y, blockIdx.x);
}

// ---- combine + ReLU: h1 = relu(p0+p1+b1) bf16, [4096][512] ----
__global__ __launch_bounds__(256) void crelu_kernel(
    const float* __restrict__ p0, const float* __restrict__ p1,
    const float* __restrict__ b1, bf16* __restrict__ h1)
{
    int i = blockIdx.x * 256 + threadIdx.x;
    float4 a = ((const float4*)p0)[i];
    float4 b = ((const float4*)p1)[i];
    int col = (i * 4) & 511;
    float4 bb = *(const float4*)(b1 + col);
    bf16x4 o;
    o[0] = (bf16)fmaxf(a.x + b.x + bb.x, 0.0f);
    o[1] = (bf16)fmaxf(a.y + b.y + bb.y, 0.0f);
    o[2] = (bf16)fmaxf(a.z + b.z + bb.z, 0.0f);
    o[3] = (bf16)fmaxf(a.w + b.w + bb.w, 0.0f);
    ((bf16x4*)h1)[i] = o;
}

// ---------------- GEMM: C = A(MxK,lda)@Bt^T + bias [+Rb/+Rf] [ReLU] ----------------
template <typename OutT, int BN, int KU, bool VFUSE, bool SPLITK>
__global__ __launch_bounds__(256) void gemm128(
    const bf16* __restrict__ A, const bf16* __restrict__ Bt,
    const float* __restrict__ bias, const bf16* __restrict__ Rb,
    const float* __restrict__ Rf, OutT* __restrict__ C, bf16* __restrict__ vT,
    int M, int N, int K, int lda, int relu)
{
    constexpr int NT = BN / 32;
    constexpr int ASTR = 128 * 32;
    constexpr int BSTR = BN * 32;
    __shared__ bf16 As[ASTR * KU];
    __shared__ bf16 Bs[BSTR * KU];

    int tid = threadIdx.x;
    int wave = tid >> 6, lane = tid & 63;
    int quad = lane >> 4, l16 = lane & 15;
    int m0 = blockIdx.y * 128, n0 = blockIdx.x * BN;
    int wm = (wave >> 1) * 64, wn = (wave & 1) * (BN / 2);
    int Keff = SPLITK ? (K >> 1) : K;
    int klo  = SPLITK ? blockIdx.z * Keff : 0;

    f32x4 acc[4][NT] = {};

    const bf16* ga = A  + (size_t)(m0 + (tid >> 2)) * lda + (tid & 3) * 8 + klo;
    const bf16* gb = Bt + (size_t)(n0 + (tid >> 2)) * K   + (tid & 3) * 8 + klo;
    bf16* lAs = As + wave * 512;
    bf16* lBs = Bs + wave * 512;

    for (int k0 = 0; k0 < Keff; k0 += 32 * KU) {
        __syncthreads();
#pragma unroll
        for (int u = 0; u < KU; ++u) {
            glds16(ga + k0 + u * 32, lAs + u * ASTR);
            glds16(ga + (size_t)64 * lda + k0 + u * 32, lAs + u * ASTR + 2048);
            glds16(gb + k0 + u * 32, lBs + u * BSTR);
            if (BN == 128) glds16(gb + (size_t)64 * K + k0 + u * 32, lBs + u * BSTR + 2048);
        }
        __syncthreads();
#pragma unroll
        for (int u = 0; u < KU; ++u) {
            bf16x8 af[4], bfr[NT];
#pragma unroll
            for (int mt = 0; mt < 4; ++mt)
                af[mt] = *(const bf16x8*)(As + u * ASTR + (wm + mt * 16 + l16) * 32 + quad * 8);
#pragma unroll
            for (int nt = 0; nt < NT; ++nt)
                bfr[nt] = *(const bf16x8*)(Bs + u * BSTR + (wn + nt * 16 + l16) * 32 + quad * 8);
#pragma unroll
            for (int mt = 0; mt < 4; ++mt)
#pragma unroll
                for (int nt = 0; nt < NT; ++nt)
                    acc[mt][nt] = __builtin_amdgcn_mfma_f32_16x16x32_bf16(af[mt], bfr[nt], acc[mt][nt], 0, 0, 0);
        }
    }

    if (SPLITK) {
        float* P = (float*)C + (size_t)blockIdx.z * M * N;
#pragma unroll
        for (int nt = 0; nt < NT; ++nt) {
            int n = n0 + wn + nt * 16 + l16;
#pragma unroll
            for (int mt = 0; mt < 4; ++mt)
#pragma unroll
                for (int r = 0; r < 4; ++r) {
                    int m = m0 + wm + mt * 16 + quad * 4 + r;
                    P[(size_t)m * N + n] = acc[mt][nt][r];
                }
        }
        return;
    }

#pragma unroll
    for (int nt = 0; nt < NT; ++nt) {
        int n = n0 + wn + nt * 16 + l16;
        float bv = bias[n];
        if (VFUSE && n >= 2048) {
            int d = n & 63, h = (n - 2048) >> 6;
#pragma unroll
            for (int mt = 0; mt < 4; ++mt) {
                int m = m0 + wm + mt * 16 + quad * 4;
                int b = m >> 11, sidx = m & 2047;
                bf16x4 pk;
#pragma unroll
                for (int r = 0; r < 4; ++r) pk[r] = (bf16)(acc[mt][nt][r] + bv);
                *(bf16x4*)(vT + (((size_t)(b * 16 + h) * 64 + d) * SEQ + sidx)) = pk;
            }
        } else {
#pragma unroll
            for (int mt = 0; mt < 4; ++mt) {
#pragma unroll
                for (int r = 0; r < 4; ++r) {
                    int m = m0 + wm + mt * 16 + quad * 4 + r;
                    float vv = acc[mt][nt][r] + bv;
                    if (Rb) vv += (float)Rb[(size_t)m * N + n];
                    if (Rf) vv += Rf[(size_t)m * N + n];
                    if (relu) vv = vv > 0.0f ? vv : 0.0f;
                    C[(size_t)m * N + n] = (OutT)vv;
                }
            }
        }
    }
}

// ---------------- Flash attention, dh=64, fixed-max softmax ----------
// grid (SEQ/128, 32 bh), block 512 = 4 q-groups (32 q) x 2 key-groups (64 keys
// of each 128-key tile). K staged in LDS (16 barriers); V loaded direct
// global->reg (L1/L2-hot); P per-wave LDS scratch; kg-merge at the end.
__global__ __launch_bounds__(512) void attn_kernel(
    const bf16* __restrict__ qkv, const bf16* __restrict__ vT, bf16* __restrict__ O)
{
    __shared__ bf16 Ks[128][72];       // [key][d]
    __shared__ bf16 Ps[8][32][72];     // per-wave P [q][key 0..63]

    int tid = threadIdx.x;
    int wave = tid >> 6, lane = tid & 63;
    int quad = lane >> 4, l16 = lane & 15;
    int qg = wave >> 1, kg = wave & 1;
    int bh = blockIdx.y, b = bh >> 4, h = bh & 15;
    int q0 = blockIdx.x * 128 + qg * 32;

    const bf16* Qb = qkv + (size_t)(b * SEQ + q0) * 3072 + h * 64;
    const bf16* Kb = qkv + (size_t)(b * SEQ) * 3072 + 1024 + h * 64;
    const bf16* Vb = vT + (size_t)bh * 64 * SEQ;

    const float c_l2 = 0.125f * LOG2E;
    bf16x8 qa[2][2];
#pragma unroll
    for (int mt = 0; mt < 2; ++mt)
#pragma unroll
        for (int hf = 0; hf < 2; ++hf) {
            bf16x8 raw = *(const bf16x8*)(Qb + (size_t)(mt * 16 + l16) * 3072 + hf * 32 + quad * 8);
            bf16x8 sc;
#pragma unroll
            for (int j = 0; j < 8; ++j) sc[j] = (bf16)((float)raw[j] * c_l2);
            qa[mt][hf] = sc;
        }

    float lsum[2] = {};
    f32x4 oacc[2][4] = {};

    int sr = tid >> 2, scol = (tid & 3) * 16;   // 128 rows x 4 chunks of 16
    const bf16* kp = Kb + (size_t)sr * 3072 + scol;
    bf16x8 kr0 = ((const bf16x8*)kp)[0];
    bf16x8 kr1 = ((const bf16x8*)kp)[1];

    bf16* PsW = &Ps[wave][0][0];
    const bf16* KsKg = &Ks[kg * 64][0];
    // V row base for this lane: d = dt*16 + l16, col offset kg*64 + quad*8
    const bf16* vrow = Vb + (size_t)l16 * SEQ + kg * 64 + quad * 8;

    for (int kt = 0; kt < SEQ; kt += 128) {
        __syncthreads();
        *(bf16x8*)&Ks[sr][scol]     = kr0;
        *(bf16x8*)&Ks[sr][scol + 8] = kr1;
        __syncthreads();
        if (kt + 128 < SEQ) {
            const bf16* kn = kp + (size_t)(kt + 128) * 3072;
            kr0 = ((const bf16x8*)kn)[0];
            kr1 = ((const bf16x8*)kn)[1];
        }

        // V direct loads (issued early; latency hides under QK+softmax)
        bf16x8 vb[4][2];
#pragma unroll
        for (int dt = 0; dt < 4; ++dt) {
            const bf16* vp = vrow + (size_t)dt * 16 * SEQ + kt;
            vb[dt][0] = *(const bf16x8*)(vp);
            vb[dt][1] = *(const bf16x8*)(vp + 32);
        }

        bf16x8 kb[4][2];
#pragma unroll
        for (int t4 = 0; t4 < 4; ++t4) {
            kb[t4][0] = *(const bf16x8*)(KsKg + (t4 * 16 + l16) * 72 + quad * 8);
            kb[t4][1] = *(const bf16x8*)(KsKg + (t4 * 16 + l16) * 72 + 32 + quad * 8);
        }

        // S^T over this wave's 64 keys: rows = keys, col = q (l16)
#pragma unroll
        for (int mt = 0; mt < 2; ++mt)
#pragma unroll
            for (int t4 = 0; t4 < 4; ++t4) {
                f32x4 c = {};
                c = __builtin_amdgcn_mfma_f32_16x16x32_bf16(kb[t4][0], qa[mt][0], c, 0, 0, 0);
                c = __builtin_amdgcn_mfma_f32_16x16x32_bf16(kb[t4][1], qa[mt][1], c, 0, 0, 0);
                bf16x4 pk;
                float psum = 0.0f;
#pragma unroll
                for (int r = 0; r < 4; ++r) {
                    float p = exp2f(c[r]);
                    psum += p;
                    pk[r] = (bf16)p;
                }
                lsum[mt] += psum;
                *(bf16x4*)(PsW + (mt * 16 + l16) * 72 + t4 * 16 + quad * 4) = pk;
            }
        // PV over this wave's 64 keys (two K=32 halves)
#pragma unroll
        for (int mt = 0; mt < 2; ++mt) {
            bf16x8 pa0 = *(const bf16x8*)(PsW + (mt * 16 + l16) * 72 + quad * 8);
            bf16x8 pa1 = *(const bf16x8*)(PsW + (mt * 16 + l16) * 72 + 32 + quad * 8);
#pragma unroll
            for (int dt = 0; dt < 4; ++dt) {
                oacc[mt][dt] = __builtin_amdgcn_mfma_f32_16x16x32_bf16(pa0, vb[dt][0], oacc[mt][dt], 0, 0, 0);
                oacc[mt][dt] = __builtin_amdgcn_mfma_f32_16x16x32_bf16(pa1, vb[dt][1], oacc[mt][dt], 0, 0, 0);
            }
        }
    }

    // cross-quad lsum reduce (per q = mt*16 + l16)
    float lr[2];
#pragma unroll
    for (int mt = 0; mt < 2; ++mt) {
        lr[mt] = lsum[mt];
        lr[mt] += __shfl_xor(lr[mt], 16);
        lr[mt] += __shfl_xor(lr[mt], 32);
    }
    // merge the two key-groups via LDS (Ks/Ps dead now)
    __syncthreads();
    float* sf = (float*)&Ps[0][0][0];          // [qg][d 64][q 32] f32 (32 KB)
    float* lb = (float*)&Ks[0][0];             // [qg][mt][16]
    if (kg == 1) {
#pragma unroll
        for (int mt = 0; mt < 2; ++mt)
#pragma unroll
            for (int dt = 0; dt < 4; ++dt)
                *(f32x4*)&sf[qg * 2048 + (dt * 16 + l16) * 32 + mt * 16 + quad * 4] = oacc[mt][dt];
        if (lane < 16) {
            lb[(qg * 2 + 0) * 16 + l16] = lr[0];
            lb[(qg * 2 + 1) * 16 + l16] = lr[1];
        }
    }
    __syncthreads();
    if (kg == 0) {
#pragma unroll
        for (int mt = 0; mt < 2; ++mt) {
            lr[mt] += lb[(qg * 2 + mt) * 16 + l16];
#pragma unroll
            for (int dt = 0; dt < 4; ++dt) {
                f32x4 other = *(const f32x4*)&sf[qg * 2048 + (dt * 16 + l16) * 32 + mt * 16 + quad * 4];
                oacc[mt][dt] += other;
            }
        }
#pragma unroll
        for (int mt = 0; mt < 2; ++mt)
#pragma unroll
            for (int r = 0; r < 4; ++r) {
                float inv = 1.0f / __shfl(lr[mt], quad * 4 + r, 16);
                int row = b * SEQ + q0 + mt * 16 + quad * 4 + r;
                bf16* op = O + (size_t)row * D_MODEL + h * 64;
#pragma unroll
                for (int dt = 0; dt < 4; ++dt)
                    op[dt * 16 + l16] = (bf16)(oacc[mt][dt][r] * inv);
            }
    }
}

// ---------------- launch ----------------
extern "C" void kernel_launch(void* const* d_in, const int* in_sizes, int n_in,
                              void* d_out, int out_size, void* d_ws, size_t ws_size,
                              hipStream_t stream)
{
    const float* x      = (const float*)d_in[0];
    const float* Wq     = (const float*)d_in[1];
    const float* bq     = (const float*)d_in[2];
    const float* Wk     = (const float*)d_in[3];
    const float* bk     = (const float*)d_in[4];
    const float* Wv     = (const float*)d_in[5];
    const float* bv     = (const float*)d_in[6];
    const float* Wo     = (const float*)d_in[7];
    const float* bo     = (const float*)d_in[8];
    const float* alpha1 = (const float*)d_in[9];
    const float* beta1  = (const float*)d_in[10];
    const float* alpha2 = (const float*)d_in[11];
    const float* beta2  = (const float*)d_in[12];
    const float* W1     = (const float*)d_in[13];
    const float* b1     = (const float*)d_in[14];
    const float* W2     = (const float*)d_in[15];
    const float* b2     = (const float*)d_in[16];

    char* ws = (char*)d_ws;
    const size_t MB = 1ull << 20;
    bf16*  Wqkv_t = (bf16*)(ws + 0 * MB);
    bf16*  Wo_t   = (bf16*)(ws + 6 * MB);
    bf16*  W1_t   = (bf16*)(ws + 8 * MB);
    bf16*  W2_t   = (bf16*)(ws + 9 * MB);
    float* b_qkv  = (float*)(ws + 10 * MB);
    bf16*  xn     = (bf16*)(ws + 11 * MB);   // 8 MB
    bf16*  qkv    = (bf16*)(ws + 19 * MB);   // 24 MB
    bf16*  vT     = (bf16*)(ws + 43 * MB);   // 8 MB
    bf16*  o      = (bf16*)(ws + 51 * MB);   // 8 MB
    float* x2     = (float*)(ws + 19 * MB);  // 16 MB over dead qkv head
    bf16*  hn     = (bf16*)(ws + 35 * MB);   // 8 MB over dead qkv tail
    float* pF1    = (float*)(ws + 43 * MB);  // 2x8 MB over dead vT+o
    bf16*  h1     = (bf16*)(ws + 11 * MB);   // 4 MB over dead xn

    const int M = NB * SEQ;

    prep_norm_kernel<<<4096 + 1292, 256, 0, stream>>>(
        x, alpha1, beta1, xn, Wq, Wk, Wv, Wo, W1, W2, bq, bk, bv,
        Wqkv_t, Wo_t, W1_t, W2_t, b_qkv);

    gemm128<bf16, 128, 2, true, false><<<dim3(24, 32), 256, 0, stream>>>(
        xn, Wqkv_t, b_qkv, nullptr, nullptr, qkv, vT, M, 3072, D_MODEL, D_MODEL, 0);

    attn_kernel<<<dim3(SEQ / 128, 32), 512, 0, stream>>>(qkv, vT, o);

    gemm128<float, 64, 2, false, false><<<dim3(16, 32), 256, 0, stream>>>(
        o, Wo_t, bo, xn, nullptr, x2, nullptr, M, D_MODEL, D_MODEL, D_MODEL, 0);

    norm_kernel<<<M, 256, 0, stream>>>(x2, alpha2, beta2, hn);

    gemm128<float, 64, 2, false, true><<<dim3(8, 32, 2), 256, 0, stream>>>(
        hn, W1_t, nullptr, nullptr, nullptr, pF1, nullptr, M, 512, D_MODEL, D_MODEL, 0);

    crelu_kernel<<<(M * 512) / 1024, 256, 0, stream>>>(
        pF1, pF1 + (size_t)M * 512, b1, h1);

    gemm128<float, 64, 2, false, false><<<dim3(16, 32), 256, 0, stream>>>(
        h1, W2_t, b2, nullptr, x2, (float*)d_out, nullptr, M, D_MODEL, 512, 512, 0);
}

// Round 10
// 271.911 us; speedup vs baseline: 1.1276x; 1.1276x over previous
//
#include <hip/hip_runtime.h>

typedef __bf16 bf16;
typedef __bf16 bf16x4 __attribute__((ext_vector_type(4)));
typedef __bf16 bf16x8 __attribute__((ext_vector_type(8)));
typedef float f32x4 __attribute__((ext_vector_type(4)));

#define D_MODEL 1024
#define SEQ 2048
#define NB 2
#define LOG2E 1.4426950408889634f

// async global->LDS, 16B per lane; LDS dest = wave-uniform base + lane*16
__device__ __forceinline__ void glds16(const bf16* g, bf16* l) {
    __builtin_amdgcn_global_load_lds(
        (const __attribute__((address_space(1))) void*)g,
        (__attribute__((address_space(3))) void*)l, 16, 0, 0);
}

// ---------------- fused prep (weights W^T + bias concat) + norm1 ----------------
__device__ __forceinline__ void tile_tcvt(
    const float* __restrict__ src, int rows, int cols, bf16* __restrict__ dst,
    int bx, int by, bf16 (*t)[72])
{
    int tid = threadIdx.x;
    int k0 = by * 64, n0 = bx * 64;
    int r = tid >> 2, c = (tid & 3) * 16;
    const float4* s = (const float4*)(src + (size_t)(k0 + r) * cols + n0 + c);
#pragma unroll
    for (int q = 0; q < 4; ++q) {
        float4 v = s[q];
        t[c + q * 4 + 0][r] = (bf16)v.x;
        t[c + q * 4 + 1][r] = (bf16)v.y;
        t[c + q * 4 + 2][r] = (bf16)v.z;
        t[c + q * 4 + 3][r] = (bf16)v.w;
    }
    __syncthreads();
    bf16* d = dst + (size_t)(n0 + r) * rows + k0 + c;
    *(bf16x8*)(d)     = *(const bf16x8*)&t[r][c];
    *(bf16x8*)(d + 8) = *(const bf16x8*)&t[r][c + 8];
}

__device__ __forceinline__ void norm_row(
    const float* __restrict__ X, const float* __restrict__ alpha,
    const float* __restrict__ beta, bf16* __restrict__ Y, int row)
{
    int tid = threadIdx.x;
    float4 v = ((const float4*)(X + (size_t)row * D_MODEL))[tid];
    float s = v.x + v.y + v.z + v.w;
    float ss = v.x*v.x + v.y*v.y + v.z*v.z + v.w*v.w;
#pragma unroll
    for (int off = 1; off < 64; off <<= 1) {
        s  += __shfl_xor(s, off, 64);
        ss += __shfl_xor(ss, off, 64);
    }
    __shared__ float sd[8];
    int wave = tid >> 6, lane = tid & 63;
    if (lane == 0) { sd[wave] = s; sd[4 + wave] = ss; }
    __syncthreads();
    s  = sd[0] + sd[1] + sd[2] + sd[3];
    ss = sd[4] + sd[5] + sd[6] + sd[7];
    float mean = s * (1.0f / 1024.0f);
    float var  = (ss - s * mean) * (1.0f / 1023.0f);
    float rs = rsqrtf(var + 1e-6f);
    float4 a = ((const float4*)alpha)[tid];
    float4 bt = ((const float4*)beta)[tid];
    bf16x4 o;
    o[0] = (bf16)(a.x * (v.x - mean) * rs + bt.x);
    o[1] = (bf16)(a.y * (v.y - mean) * rs + bt.y);
    o[2] = (bf16)(a.z * (v.z - mean) * rs + bt.z);
    o[3] = (bf16)(a.w * (v.w - mean) * rs + bt.w);
    *(bf16x4*)(Y + (size_t)row * D_MODEL + tid * 4) = o;
}

__global__ __launch_bounds__(256) void prep_norm_kernel(
    const float* __restrict__ x, const float* __restrict__ alpha1,
    const float* __restrict__ beta1, bf16* __restrict__ xn,
    const float* __restrict__ Wq, const float* __restrict__ Wk,
    const float* __restrict__ Wv, const float* __restrict__ Wo,
    const float* __restrict__ W1, const float* __restrict__ W2,
    const float* __restrict__ bq, const float* __restrict__ bk,
    const float* __restrict__ bv,
    bf16* __restrict__ Wqkv_t, bf16* __restrict__ Wo_t,
    bf16* __restrict__ W1_t, bf16* __restrict__ W2_t,
    float* __restrict__ b_qkv)
{
    __shared__ bf16 t[64][72];
    int id = blockIdx.x;
    if (id < 4096) {
        norm_row(x, alpha1, beta1, xn, id);
        return;
    }
    id -= 4096;
    if (id < 1024) {
        int which = id >> 8, tile = id & 255;
        const float* src = which == 0 ? Wq : which == 1 ? Wk : which == 2 ? Wv : Wo;
        bf16* dst = which == 3 ? Wo_t : Wqkv_t + (size_t)which * 1024 * 1024;
        tile_tcvt(src, 1024, 1024, dst, tile & 15, tile >> 4, t);
    } else if (id < 1152) {
        int tile = id - 1024;
        tile_tcvt(W1, 1024, 512, W1_t, tile & 7, tile >> 3, t);
    } else if (id < 1280) {
        int tile = id - 1152;
        tile_tcvt(W2, 512, 1024, W2_t, tile & 15, tile >> 4, t);
    } else {
        int i = (id - 1280) * 256 + threadIdx.x;
        float v;
        if (i < 1024) v = bq[i];
        else if (i < 2048) v = bk[i - 1024];
        else v = bv[i - 2048];
        b_qkv[i] = v;
    }
}

// ---------------- LayerNorm standalone (norm2) ----------------
__global__ __launch_bounds__(256) void norm_kernel(
    const float* __restrict__ X, const float* __restrict__ alpha,
    const float* __restrict__ beta, bf16* __restrict__ Y)
{
    norm_row(X, alpha, beta, Y, blockIdx.x);
}

// ---------------- GEMM: C = A(MxK,lda)@Bt^T + bias [+Rb/+Rf] [ReLU] ----------------
template <typename OutT, int BN, int KU, bool VFUSE>
__global__ __launch_bounds__(256) void gemm128(
    const bf16* __restrict__ A, const bf16* __restrict__ Bt,
    const float* __restrict__ bias, const bf16* __restrict__ Rb,
    const float* __restrict__ Rf, OutT* __restrict__ C, bf16* __restrict__ vT,
    int M, int N, int K, int lda, int relu)
{
    constexpr int NT = BN / 32;
    constexpr int ASTR = 128 * 32;
    constexpr int BSTR = BN * 32;
    __shared__ bf16 As[ASTR * KU];
    __shared__ bf16 Bs[BSTR * KU];

    int tid = threadIdx.x;
    int wave = tid >> 6, lane = tid & 63;
    int quad = lane >> 4, l16 = lane & 15;
    int m0 = blockIdx.y * 128, n0 = blockIdx.x * BN;
    int wm = (wave >> 1) * 64, wn = (wave & 1) * (BN / 2);

    f32x4 acc[4][NT] = {};

    const bf16* ga = A  + (size_t)(m0 + (tid >> 2)) * lda + (tid & 3) * 8;
    const bf16* gb = Bt + (size_t)(n0 + (tid >> 2)) * K   + (tid & 3) * 8;
    bf16* lAs = As + wave * 512;
    bf16* lBs = Bs + wave * 512;

    for (int k0 = 0; k0 < K; k0 += 32 * KU) {
        __syncthreads();
#pragma unroll
        for (int u = 0; u < KU; ++u) {
            glds16(ga + k0 + u * 32, lAs + u * ASTR);
            glds16(ga + (size_t)64 * lda + k0 + u * 32, lAs + u * ASTR + 2048);
            glds16(gb + k0 + u * 32, lBs + u * BSTR);
            if (BN == 128) glds16(gb + (size_t)64 * K + k0 + u * 32, lBs + u * BSTR + 2048);
        }
        __syncthreads();
#pragma unroll
        for (int u = 0; u < KU; ++u) {
            bf16x8 af[4], bfr[NT];
#pragma unroll
            for (int mt = 0; mt < 4; ++mt)
                af[mt] = *(const bf16x8*)(As + u * ASTR + (wm + mt * 16 + l16) * 32 + quad * 8);
#pragma unroll
            for (int nt = 0; nt < NT; ++nt)
                bfr[nt] = *(const bf16x8*)(Bs + u * BSTR + (wn + nt * 16 + l16) * 32 + quad * 8);
#pragma unroll
            for (int mt = 0; mt < 4; ++mt)
#pragma unroll
                for (int nt = 0; nt < NT; ++nt)
                    acc[mt][nt] = __builtin_amdgcn_mfma_f32_16x16x32_bf16(af[mt], bfr[nt], acc[mt][nt], 0, 0, 0);
        }
    }

#pragma unroll
    for (int nt = 0; nt < NT; ++nt) {
        int n = n0 + wn + nt * 16 + l16;
        float bv = bias[n];
        if (VFUSE && n >= 2048) {
            int d = n & 63, h = (n - 2048) >> 6;
#pragma unroll
            for (int mt = 0; mt < 4; ++mt) {
                int m = m0 + wm + mt * 16 + quad * 4;
                int b = m >> 11, sidx = m & 2047;
                bf16x4 pk;
#pragma unroll
                for (int r = 0; r < 4; ++r) pk[r] = (bf16)(acc[mt][nt][r] + bv);
                *(bf16x4*)(vT + (((size_t)(b * 16 + h) * 64 + d) * SEQ + sidx)) = pk;
            }
        } else {
#pragma unroll
            for (int mt = 0; mt < 4; ++mt) {
#pragma unroll
                for (int r = 0; r < 4; ++r) {
                    int m = m0 + wm + mt * 16 + quad * 4 + r;
                    float vv = acc[mt][nt][r] + bv;
                    if (Rb) vv += (float)Rb[(size_t)m * N + n];
                    if (Rf) vv += Rf[(size_t)m * N + n];
                    if (relu) vv = vv > 0.0f ? vv : 0.0f;
                    C[(size_t)m * N + n] = (OutT)vv;
                }
            }
        }
    }
}

// ---------------- Flash attention (R8 config), dh=64, fixed-max softmax --------
// grid: (SEQ/128, 32 bh), block 512 = 4 q-groups (32 q) x 2 key-groups
// (32 keys of each 64-key tile). K,V staged in LDS; per-wave partial O/lsum;
// LDS merge at the end. S^T operand order -> packed bf16x4 Ps writes.
__global__ __launch_bounds__(512) void attn_kernel(
    const bf16* __restrict__ qkv, const bf16* __restrict__ vT, bf16* __restrict__ O)
{
    __shared__ __align__(16) char smem[38912];
    bf16* Ks = (bf16*)smem;              // [64][72]
    bf16* Vt = (bf16*)(smem + 9216);     // [64][72]
    bf16* Ps = (bf16*)(smem + 18432);    // [8 waves][32 q][40 keys-padded]

    int tid = threadIdx.x;
    int wave = tid >> 6, lane = tid & 63;
    int quad = lane >> 4, l16 = lane & 15;
    int qg = wave >> 1, kg = wave & 1;
    int bh = blockIdx.y, b = bh >> 4, h = bh & 15;
    int q0 = blockIdx.x * 128 + qg * 32;

    const bf16* Qb = qkv + (size_t)(b * SEQ + q0) * 3072 + h * 64;
    const bf16* Kb = qkv + (size_t)(b * SEQ) * 3072 + 1024 + h * 64;
    const bf16* Vb = vT + (size_t)bh * 64 * SEQ;

    const float c_l2 = 0.125f * LOG2E;
    bf16x8 qa[2][2];
#pragma unroll
    for (int mt = 0; mt < 2; ++mt)
#pragma unroll
        for (int hf = 0; hf < 2; ++hf) {
            bf16x8 raw = *(const bf16x8*)(Qb + (size_t)(mt * 16 + l16) * 3072 + hf * 32 + quad * 8);
            bf16x8 sc;
#pragma unroll
            for (int j = 0; j < 8; ++j) sc[j] = (bf16)((float)raw[j] * c_l2);
            qa[mt][hf] = sc;
        }

    float lsum[2] = {};
    f32x4 oacc[2][4] = {};

    int sr = tid >> 3, scol = (tid & 7) * 8;   // 64 rows x 8 chunks (512 thr)
    const bf16* kp = Kb + (size_t)sr * 3072 + scol;
    const bf16* vp = Vb + (size_t)sr * SEQ + scol;
    bf16x8 kr = *(const bf16x8*)kp;
    bf16x8 vr = *(const bf16x8*)vp;

    bf16* PsW = Ps + wave * 32 * 40;
    const bf16* KsKg = Ks + kg * 32 * 72;

    for (int kt = 0; kt < SEQ; kt += 64) {
        __syncthreads();
        *(bf16x8*)(Ks + sr * 72 + scol) = kr;
        *(bf16x8*)(Vt + sr * 72 + scol) = vr;
        __syncthreads();
        if (kt + 64 < SEQ) {                    // prefetch next tile
            kr = *(const bf16x8*)(kp + (size_t)(kt + 64) * 3072);
            vr = *(const bf16x8*)(vp + kt + 64);
        }

        bf16x8 kb[2][2], vb[4];
#pragma unroll
        for (int t4 = 0; t4 < 2; ++t4) {
            kb[t4][0] = *(const bf16x8*)(KsKg + (t4 * 16 + l16) * 72 + quad * 8);
            kb[t4][1] = *(const bf16x8*)(KsKg + (t4 * 16 + l16) * 72 + 32 + quad * 8);
        }
#pragma unroll
        for (int dt = 0; dt < 4; ++dt)
            vb[dt] = *(const bf16x8*)(Vt + (dt * 16 + l16) * 72 + kg * 32 + quad * 8);

        // S^T over this wave's 32 keys: rows = keys, col = q (l16)
#pragma unroll
        for (int mt = 0; mt < 2; ++mt)
#pragma unroll
            for (int t4 = 0; t4 < 2; ++t4) {
                f32x4 c = {};
                c = __builtin_amdgcn_mfma_f32_16x16x32_bf16(kb[t4][0], qa[mt][0], c, 0, 0, 0);
                c = __builtin_amdgcn_mfma_f32_16x16x32_bf16(kb[t4][1], qa[mt][1], c, 0, 0, 0);
                bf16x4 pk;
                float psum = 0.0f;
#pragma unroll
                for (int r = 0; r < 4; ++r) {
                    float p = exp2f(c[r]);
                    psum += p;
                    pk[r] = (bf16)p;
                }
                lsum[mt] += psum;
                *(bf16x4*)(PsW + (mt * 16 + l16) * 40 + t4 * 16 + quad * 4) = pk;
            }
        // PV over this wave's 32 keys (K=32 mfma)
#pragma unroll
        for (int mt = 0; mt < 2; ++mt) {
            bf16x8 pa = *(const bf16x8*)(PsW + (mt * 16 + l16) * 40 + quad * 8);
#pragma unroll
            for (int dt = 0; dt < 4; ++dt)
                oacc[mt][dt] = __builtin_amdgcn_mfma_f32_16x16x32_bf16(pa, vb[dt], oacc[mt][dt], 0, 0, 0);
        }
    }

    // cross-quad lsum reduce (per q = mt*16 + l16)
    float lr[2];
#pragma unroll
    for (int mt = 0; mt < 2; ++mt) {
        lr[mt] = lsum[mt];
        lr[mt] += __shfl_xor(lr[mt], 16);
        lr[mt] += __shfl_xor(lr[mt], 32);
    }
    // merge the two key-groups via LDS (Ks/Vt/Ps dead now)
    __syncthreads();
    float* sf = (float*)smem;                  // [qg][d 64][q 32]
    float* lb = sf + 8192;                     // [qg][mt][16]
    if (kg == 1) {
#pragma unroll
        for (int mt = 0; mt < 2; ++mt)
#pragma unroll
            for (int dt = 0; dt < 4; ++dt)
                *(f32x4*)&sf[qg * 2048 + (dt * 16 + l16) * 32 + mt * 16 + quad * 4] = oacc[mt][dt];
        if (lane < 16) {
            lb[(qg * 2 + 0) * 16 + l16] = lr[0];
            lb[(qg * 2 + 1) * 16 + l16] = lr[1];
        }
    }
    __syncthreads();
    if (kg == 0) {
#pragma unroll
        for (int mt = 0; mt < 2; ++mt) {
            lr[mt] += lb[(qg * 2 + mt) * 16 + l16];
#pragma unroll
            for (int dt = 0; dt < 4; ++dt) {
                f32x4 other = *(const f32x4*)&sf[qg * 2048 + (dt * 16 + l16) * 32 + mt * 16 + quad * 4];
                oacc[mt][dt] += other;
            }
        }
#pragma unroll
        for (int mt = 0; mt < 2; ++mt)
#pragma unroll
            for (int r = 0; r < 4; ++r) {
                float inv = 1.0f / __shfl(lr[mt], quad * 4 + r, 16);
                int row = b * SEQ + q0 + mt * 16 + quad * 4 + r;
                bf16* op = O + (size_t)row * D_MODEL + h * 64;
#pragma unroll
                for (int dt = 0; dt < 4; ++dt)
                    op[dt * 16 + l16] = (bf16)(oacc[mt][dt][r] * inv);
            }
    }
}

// ---------------- launch ----------------
extern "C" void kernel_launch(void* const* d_in, const int* in_sizes, int n_in,
                              void* d_out, int out_size, void* d_ws, size_t ws_size,
                              hipStream_t stream)
{
    const float* x      = (const float*)d_in[0];
    const float* Wq     = (const float*)d_in[1];
    const float* bq     = (const float*)d_in[2];
    const float* Wk     = (const float*)d_in[3];
    const float* bk     = (const float*)d_in[4];
    const float* Wv     = (const float*)d_in[5];
    const float* bv     = (const float*)d_in[6];
    const float* Wo     = (const float*)d_in[7];
    const float* bo     = (const float*)d_in[8];
    const float* alpha1 = (const float*)d_in[9];
    const float* beta1  = (const float*)d_in[10];
    const float* alpha2 = (const float*)d_in[11];
    const float* beta2  = (const float*)d_in[12];
    const float* W1     = (const float*)d_in[13];
    const float* b1     = (const float*)d_in[14];
    const float* W2     = (const float*)d_in[15];
    const float* b2     = (const float*)d_in[16];

    char* ws = (char*)d_ws;
    const size_t MB = 1ull << 20;
    bf16*  Wqkv_t = (bf16*)(ws + 0 * MB);    // 6 MB
    bf16*  Wo_t   = (bf16*)(ws + 6 * MB);    // 2 MB
    bf16*  W1_t   = (bf16*)(ws + 8 * MB);    // 1 MB
    bf16*  W2_t   = (bf16*)(ws + 9 * MB);    // 1 MB
    float* b_qkv  = (float*)(ws + 10 * MB);
    bf16*  xn     = (bf16*)(ws + 11 * MB);   // 8 MB (live until Wo epilogue)
    bf16*  qkv    = (bf16*)(ws + 19 * MB);   // 24 MB (q,k live until attn)
    bf16*  vT     = (bf16*)(ws + 43 * MB);   // 8 MB (dead after attn)
    bf16*  o      = (bf16*)(ws + 51 * MB);   // 8 MB (dead after Wo)
    float* x2     = (float*)(ws + 19 * MB);  // fp32 16 MB over dead qkv head
    bf16*  hn     = (bf16*)(ws + 35 * MB);   // 8 MB over dead qkv tail
    bf16*  h1     = (bf16*)(ws + 11 * MB);   // 4 MB over dead xn

    const int M = NB * SEQ;

    prep_norm_kernel<<<4096 + 1292, 256, 0, stream>>>(
        x, alpha1, beta1, xn, Wq, Wk, Wv, Wo, W1, W2, bq, bk, bv,
        Wqkv_t, Wo_t, W1_t, W2_t, b_qkv);

    // fused QKV GEMM, KU=2, V written transposed
    gemm128<bf16, 128, 2, true><<<dim3(24, 32), 256, 0, stream>>>(
        xn, Wqkv_t, b_qkv, nullptr, nullptr, qkv, vT, M, 3072, D_MODEL, D_MODEL, 0);

    attn_kernel<<<dim3(SEQ / 128, 32), 512, 0, stream>>>(qkv, vT, o);

    // x2 = xn + o @ Wo + bo  (BN=64, KU=2)
    gemm128<float, 64, 2, false><<<dim3(16, 32), 256, 0, stream>>>(
        o, Wo_t, bo, xn, nullptr, x2, nullptr, M, D_MODEL, D_MODEL, D_MODEL, 0);

    norm_kernel<<<M, 256, 0, stream>>>(x2, alpha2, beta2, hn);

    // h1 = relu(hn @ W1 + b1)  (non-split, bias+ReLU fused, 256 blocks)
    gemm128<bf16, 64, 2, false><<<dim3(8, 32), 256, 0, stream>>>(
        hn, W1_t, b1, nullptr, nullptr, h1, nullptr, M, 512, D_MODEL, D_MODEL, 1);

    // out = x2 + h1 @ W2 + b2  (BN=64, KU=2)
    gemm128<float, 64, 2, false><<<dim3(16, 32), 256, 0, stream>>>(
        h1, W2_t, b2, nullptr, x2, (float*)d_out, nullptr, M, D_MODEL, 512, 512, 0);
}

// Round 11
// 267.188 us; speedup vs baseline: 1.1476x; 1.0177x over previous
//
#include <hip/hip_runtime.h>

typedef __bf16 bf16;
typedef __bf16 bf16x4 __attribute__((ext_vector_type(4)));
typedef __bf16 bf16x8 __attribute__((ext_vector_type(8)));
typedef float f32x4 __attribute__((ext_vector_type(4)));

#define D_MODEL 1024
#define SEQ 2048
#define NB 2
#define LOG2E 1.4426950408889634f

// async global->LDS, 16B per lane; LDS dest = wave-uniform base + lane*16
__device__ __forceinline__ void glds16(const bf16* g, bf16* l) {
    __builtin_amdgcn_global_load_lds(
        (const __attribute__((address_space(1))) void*)g,
        (__attribute__((address_space(3))) void*)l, 16, 0, 0);
}

// ---------------- fused prep (weights W^T + bias concat) + norm1 ----------------
__device__ __forceinline__ void tile_tcvt(
    const float* __restrict__ src, int rows, int cols, bf16* __restrict__ dst,
    int bx, int by, bf16 (*t)[72])
{
    int tid = threadIdx.x;
    int k0 = by * 64, n0 = bx * 64;
    int r = tid >> 2, c = (tid & 3) * 16;
    const float4* s = (const float4*)(src + (size_t)(k0 + r) * cols + n0 + c);
#pragma unroll
    for (int q = 0; q < 4; ++q) {
        float4 v = s[q];
        t[c + q * 4 + 0][r] = (bf16)v.x;
        t[c + q * 4 + 1][r] = (bf16)v.y;
        t[c + q * 4 + 2][r] = (bf16)v.z;
        t[c + q * 4 + 3][r] = (bf16)v.w;
    }
    __syncthreads();
    bf16* d = dst + (size_t)(n0 + r) * rows + k0 + c;
    *(bf16x8*)(d)     = *(const bf16x8*)&t[r][c];
    *(bf16x8*)(d + 8) = *(const bf16x8*)&t[r][c + 8];
}

__device__ __forceinline__ void norm_row(
    const float* __restrict__ X, const float* __restrict__ alpha,
    const float* __restrict__ beta, bf16* __restrict__ Y, int row)
{
    int tid = threadIdx.x;
    float4 v = ((const float4*)(X + (size_t)row * D_MODEL))[tid];
    float s = v.x + v.y + v.z + v.w;
    float ss = v.x*v.x + v.y*v.y + v.z*v.z + v.w*v.w;
#pragma unroll
    for (int off = 1; off < 64; off <<= 1) {
        s  += __shfl_xor(s, off, 64);
        ss += __shfl_xor(ss, off, 64);
    }
    __shared__ float sd[8];
    int wave = tid >> 6, lane = tid & 63;
    if (lane == 0) { sd[wave] = s; sd[4 + wave] = ss; }
    __syncthreads();
    s  = sd[0] + sd[1] + sd[2] + sd[3];
    ss = sd[4] + sd[5] + sd[6] + sd[7];
    float mean = s * (1.0f / 1024.0f);
    float var  = (ss - s * mean) * (1.0f / 1023.0f);
    float rs = rsqrtf(var + 1e-6f);
    float4 a = ((const float4*)alpha)[tid];
    float4 bt = ((const float4*)beta)[tid];
    bf16x4 o;
    o[0] = (bf16)(a.x * (v.x - mean) * rs + bt.x);
    o[1] = (bf16)(a.y * (v.y - mean) * rs + bt.y);
    o[2] = (bf16)(a.z * (v.z - mean) * rs + bt.z);
    o[3] = (bf16)(a.w * (v.w - mean) * rs + bt.w);
    *(bf16x4*)(Y + (size_t)row * D_MODEL + tid * 4) = o;
}

__global__ __launch_bounds__(256) void prep_norm_kernel(
    const float* __restrict__ x, const float* __restrict__ alpha1,
    const float* __restrict__ beta1, bf16* __restrict__ xn,
    const float* __restrict__ Wq, const float* __restrict__ Wk,
    const float* __restrict__ Wv, const float* __restrict__ Wo,
    const float* __restrict__ W1, const float* __restrict__ W2,
    const float* __restrict__ bq, const float* __restrict__ bk,
    const float* __restrict__ bv,
    bf16* __restrict__ Wqkv_t, bf16* __restrict__ Wo_t,
    bf16* __restrict__ W1_t, bf16* __restrict__ W2_t,
    float* __restrict__ b_qkv)
{
    __shared__ bf16 t[64][72];
    int id = blockIdx.x;
    if (id < 4096) {
        norm_row(x, alpha1, beta1, xn, id);
        return;
    }
    id -= 4096;
    if (id < 1024) {
        int which = id >> 8, tile = id & 255;
        const float* src = which == 0 ? Wq : which == 1 ? Wk : which == 2 ? Wv : Wo;
        bf16* dst = which == 3 ? Wo_t : Wqkv_t + (size_t)which * 1024 * 1024;
        tile_tcvt(src, 1024, 1024, dst, tile & 15, tile >> 4, t);
    } else if (id < 1152) {
        int tile = id - 1024;
        tile_tcvt(W1, 1024, 512, W1_t, tile & 7, tile >> 3, t);
    } else if (id < 1280) {
        int tile = id - 1152;
        tile_tcvt(W2, 512, 1024, W2_t, tile & 15, tile >> 4, t);
    } else {
        int i = (id - 1280) * 256 + threadIdx.x;
        float v;
        if (i < 1024) v = bq[i];
        else if (i < 2048) v = bk[i - 1024];
        else v = bv[i - 2048];
        b_qkv[i] = v;
    }
}

// ---------------- LayerNorm standalone (norm2) ----------------
__global__ __launch_bounds__(256) void norm_kernel(
    const float* __restrict__ X, const float* __restrict__ alpha,
    const float* __restrict__ beta, bf16* __restrict__ Y)
{
    norm_row(X, alpha, beta, Y, blockIdx.x);
}

// ---- combine + ReLU: h1 = relu(p0+p1+b1) bf16, [4096][512] ----
__global__ __launch_bounds__(256) void crelu_kernel(
    const float* __restrict__ p0, const float* __restrict__ p1,
    const float* __restrict__ b1, bf16* __restrict__ h1)
{
    int i = blockIdx.x * 256 + threadIdx.x;
    float4 a = ((const float4*)p0)[i];
    float4 b = ((const float4*)p1)[i];
    int col = (i * 4) & 511;
    float4 bb = *(const float4*)(b1 + col);
    bf16x4 o;
    o[0] = (bf16)fmaxf(a.x + b.x + bb.x, 0.0f);
    o[1] = (bf16)fmaxf(a.y + b.y + bb.y, 0.0f);
    o[2] = (bf16)fmaxf(a.z + b.z + bb.z, 0.0f);
    o[3] = (bf16)fmaxf(a.w + b.w + bb.w, 0.0f);
    ((bf16x4*)h1)[i] = o;
}

// ---------------- GEMM: C = A(MxK,lda)@Bt^T + bias [+Rb/+Rf] [ReLU] ----------------
// Tile 128 x BN, K-step 32*KU, 4 waves, mfma 16x16x32.
// SPLITK: grid.z=2 halves of K, raw fp32 partial out.
// VFUSE: n>=2048 columns (V proj) written transposed into vT[bh][d][s].
template <typename OutT, int BN, int KU, bool VFUSE, bool SPLITK>
__global__ __launch_bounds__(256) void gemm128(
    const bf16* __restrict__ A, const bf16* __restrict__ Bt,
    const float* __restrict__ bias, const bf16* __restrict__ Rb,
    const float* __restrict__ Rf, OutT* __restrict__ C, bf16* __restrict__ vT,
    int M, int N, int K, int lda, int relu)
{
    constexpr int NT = BN / 32;
    constexpr int ASTR = 128 * 32;
    constexpr int BSTR = BN * 32;
    __shared__ bf16 As[ASTR * KU];
    __shared__ bf16 Bs[BSTR * KU];

    int tid = threadIdx.x;
    int wave = tid >> 6, lane = tid & 63;
    int quad = lane >> 4, l16 = lane & 15;
    int m0 = blockIdx.y * 128, n0 = blockIdx.x * BN;
    int wm = (wave >> 1) * 64, wn = (wave & 1) * (BN / 2);
    int Keff = SPLITK ? (K >> 1) : K;
    int klo  = SPLITK ? blockIdx.z * Keff : 0;

    f32x4 acc[4][NT] = {};

    const bf16* ga = A  + (size_t)(m0 + (tid >> 2)) * lda + (tid & 3) * 8 + klo;
    const bf16* gb = Bt + (size_t)(n0 + (tid >> 2)) * K   + (tid & 3) * 8 + klo;
    bf16* lAs = As + wave * 512;
    bf16* lBs = Bs + wave * 512;

    for (int k0 = 0; k0 < Keff; k0 += 32 * KU) {
        __syncthreads();
#pragma unroll
        for (int u = 0; u < KU; ++u) {
            glds16(ga + k0 + u * 32, lAs + u * ASTR);
            glds16(ga + (size_t)64 * lda + k0 + u * 32, lAs + u * ASTR + 2048);
            glds16(gb + k0 + u * 32, lBs + u * BSTR);
            if (BN == 128) glds16(gb + (size_t)64 * K + k0 + u * 32, lBs + u * BSTR + 2048);
        }
        __syncthreads();
#pragma unroll
        for (int u = 0; u < KU; ++u) {
            bf16x8 af[4], bfr[NT];
#pragma unroll
            for (int mt = 0; mt < 4; ++mt)
                af[mt] = *(const bf16x8*)(As + u * ASTR + (wm + mt * 16 + l16) * 32 + quad * 8);
#pragma unroll
            for (int nt = 0; nt < NT; ++nt)
                bfr[nt] = *(const bf16x8*)(Bs + u * BSTR + (wn + nt * 16 + l16) * 32 + quad * 8);
#pragma unroll
            for (int mt = 0; mt < 4; ++mt)
#pragma unroll
                for (int nt = 0; nt < NT; ++nt)
                    acc[mt][nt] = __builtin_amdgcn_mfma_f32_16x16x32_bf16(af[mt], bfr[nt], acc[mt][nt], 0, 0, 0);
        }
    }

    if (SPLITK) {
        float* P = (float*)C + (size_t)blockIdx.z * M * N;
#pragma unroll
        for (int nt = 0; nt < NT; ++nt) {
            int n = n0 + wn + nt * 16 + l16;
#pragma unroll
            for (int mt = 0; mt < 4; ++mt)
#pragma unroll
                for (int r = 0; r < 4; ++r) {
                    int m = m0 + wm + mt * 16 + quad * 4 + r;
                    P[(size_t)m * N + n] = acc[mt][nt][r];
                }
        }
        return;
    }

#pragma unroll
    for (int nt = 0; nt < NT; ++nt) {
        int n = n0 + wn + nt * 16 + l16;
        float bv = bias[n];
        if (VFUSE && n >= 2048) {
            int d = n & 63, h = (n - 2048) >> 6;
#pragma unroll
            for (int mt = 0; mt < 4; ++mt) {
                int m = m0 + wm + mt * 16 + quad * 4;
                int b = m >> 11, sidx = m & 2047;
                bf16x4 pk;
#pragma unroll
                for (int r = 0; r < 4; ++r) pk[r] = (bf16)(acc[mt][nt][r] + bv);
                *(bf16x4*)(vT + (((size_t)(b * 16 + h) * 64 + d) * SEQ + sidx)) = pk;
            }
        } else {
#pragma unroll
            for (int mt = 0; mt < 4; ++mt) {
#pragma unroll
                for (int r = 0; r < 4; ++r) {
                    int m = m0 + wm + mt * 16 + quad * 4 + r;
                    float vv = acc[mt][nt][r] + bv;
                    if (Rb) vv += (float)Rb[(size_t)m * N + n];
                    if (Rf) vv += Rf[(size_t)m * N + n];
                    if (relu) vv = vv > 0.0f ? vv : 0.0f;
                    C[(size_t)m * N + n] = (OutT)vv;
                }
            }
        }
    }
}

// ---------------- Flash attention (R8 config), dh=64, fixed-max softmax --------
// grid: (SEQ/128, 32 bh), block 512 = 4 q-groups (32 q) x 2 key-groups
// (32 keys of each 64-key tile). K,V staged in LDS; per-wave partial O/lsum;
// LDS merge at the end. S^T operand order -> packed bf16x4 Ps writes.
__global__ __launch_bounds__(512) void attn_kernel(
    const bf16* __restrict__ qkv, const bf16* __restrict__ vT, bf16* __restrict__ O)
{
    __shared__ __align__(16) char smem[38912];
    bf16* Ks = (bf16*)smem;              // [64][72]
    bf16* Vt = (bf16*)(smem + 9216);     // [64][72]
    bf16* Ps = (bf16*)(smem + 18432);    // [8 waves][32 q][40 keys-padded]

    int tid = threadIdx.x;
    int wave = tid >> 6, lane = tid & 63;
    int quad = lane >> 4, l16 = lane & 15;
    int qg = wave >> 1, kg = wave & 1;
    int bh = blockIdx.y, b = bh >> 4, h = bh & 15;
    int q0 = blockIdx.x * 128 + qg * 32;

    const bf16* Qb = qkv + (size_t)(b * SEQ + q0) * 3072 + h * 64;
    const bf16* Kb = qkv + (size_t)(b * SEQ) * 3072 + 1024 + h * 64;
    const bf16* Vb = vT + (size_t)bh * 64 * SEQ;

    const float c_l2 = 0.125f * LOG2E;
    bf16x8 qa[2][2];
#pragma unroll
    for (int mt = 0; mt < 2; ++mt)
#pragma unroll
        for (int hf = 0; hf < 2; ++hf) {
            bf16x8 raw = *(const bf16x8*)(Qb + (size_t)(mt * 16 + l16) * 3072 + hf * 32 + quad * 8);
            bf16x8 sc;
#pragma unroll
            for (int j = 0; j < 8; ++j) sc[j] = (bf16)((float)raw[j] * c_l2);
            qa[mt][hf] = sc;
        }

    float lsum[2] = {};
    f32x4 oacc[2][4] = {};

    int sr = tid >> 3, scol = (tid & 7) * 8;   // 64 rows x 8 chunks (512 thr)
    const bf16* kp = Kb + (size_t)sr * 3072 + scol;
    const bf16* vp = Vb + (size_t)sr * SEQ + scol;
    bf16x8 kr = *(const bf16x8*)kp;
    bf16x8 vr = *(const bf16x8*)vp;

    bf16* PsW = Ps + wave * 32 * 40;
    const bf16* KsKg = Ks + kg * 32 * 72;

    for (int kt = 0; kt < SEQ; kt += 64) {
        __syncthreads();
        *(bf16x8*)(Ks + sr * 72 + scol) = kr;
        *(bf16x8*)(Vt + sr * 72 + scol) = vr;
        __syncthreads();
        if (kt + 64 < SEQ) {                    // prefetch next tile
            kr = *(const bf16x8*)(kp + (size_t)(kt + 64) * 3072);
            vr = *(const bf16x8*)(vp + kt + 64);
        }

        bf16x8 kb[2][2], vb[4];
#pragma unroll
        for (int t4 = 0; t4 < 2; ++t4) {
            kb[t4][0] = *(const bf16x8*)(KsKg + (t4 * 16 + l16) * 72 + quad * 8);
            kb[t4][1] = *(const bf16x8*)(KsKg + (t4 * 16 + l16) * 72 + 32 + quad * 8);
        }
#pragma unroll
        for (int dt = 0; dt < 4; ++dt)
            vb[dt] = *(const bf16x8*)(Vt + (dt * 16 + l16) * 72 + kg * 32 + quad * 8);

        // S^T over this wave's 32 keys: rows = keys, col = q (l16)
#pragma unroll
        for (int mt = 0; mt < 2; ++mt)
#pragma unroll
            for (int t4 = 0; t4 < 2; ++t4) {
                f32x4 c = {};
                c = __builtin_amdgcn_mfma_f32_16x16x32_bf16(kb[t4][0], qa[mt][0], c, 0, 0, 0);
                c = __builtin_amdgcn_mfma_f32_16x16x32_bf16(kb[t4][1], qa[mt][1], c, 0, 0, 0);
                bf16x4 pk;
                float psum = 0.0f;
#pragma unroll
                for (int r = 0; r < 4; ++r) {
                    float p = exp2f(c[r]);
                    psum += p;
                    pk[r] = (bf16)p;
                }
                lsum[mt] += psum;
                *(bf16x4*)(PsW + (mt * 16 + l16) * 40 + t4 * 16 + quad * 4) = pk;
            }
        // PV over this wave's 32 keys (K=32 mfma)
#pragma unroll
        for (int mt = 0; mt < 2; ++mt) {
            bf16x8 pa = *(const bf16x8*)(PsW + (mt * 16 + l16) * 40 + quad * 8);
#pragma unroll
            for (int dt = 0; dt < 4; ++dt)
                oacc[mt][dt] = __builtin_amdgcn_mfma_f32_16x16x32_bf16(pa, vb[dt], oacc[mt][dt], 0, 0, 0);
        }
    }

    // cross-quad lsum reduce (per q = mt*16 + l16)
    float lr[2];
#pragma unroll
    for (int mt = 0; mt < 2; ++mt) {
        lr[mt] = lsum[mt];
        lr[mt] += __shfl_xor(lr[mt], 16);
        lr[mt] += __shfl_xor(lr[mt], 32);
    }
    // merge the two key-groups via LDS (Ks/Vt/Ps dead now)
    __syncthreads();
    float* sf = (float*)smem;                  // [qg][d 64][q 32]
    float* lb = sf + 8192;                     // [qg][mt][16]
    if (kg == 1) {
#pragma unroll
        for (int mt = 0; mt < 2; ++mt)
#pragma unroll
            for (int dt = 0; dt < 4; ++dt)
                *(f32x4*)&sf[qg * 2048 + (dt * 16 + l16) * 32 + mt * 16 + quad * 4] = oacc[mt][dt];
        if (lane < 16) {
            lb[(qg * 2 + 0) * 16 + l16] = lr[0];
            lb[(qg * 2 + 1) * 16 + l16] = lr[1];
        }
    }
    __syncthreads();
    if (kg == 0) {
#pragma unroll
        for (int mt = 0; mt < 2; ++mt) {
            lr[mt] += lb[(qg * 2 + mt) * 16 + l16];
#pragma unroll
            for (int dt = 0; dt < 4; ++dt) {
                f32x4 other = *(const f32x4*)&sf[qg * 2048 + (dt * 16 + l16) * 32 + mt * 16 + quad * 4];
                oacc[mt][dt] += other;
            }
        }
#pragma unroll
        for (int mt = 0; mt < 2; ++mt)
#pragma unroll
            for (int r = 0; r < 4; ++r) {
                float inv = 1.0f / __shfl(lr[mt], quad * 4 + r, 16);
                int row = b * SEQ + q0 + mt * 16 + quad * 4 + r;
                bf16* op = O + (size_t)row * D_MODEL + h * 64;
#pragma unroll
                for (int dt = 0; dt < 4; ++dt)
                    op[dt * 16 + l16] = (bf16)(oacc[mt][dt][r] * inv);
            }
    }
}

// ---------------- launch ----------------
extern "C" void kernel_launch(void* const* d_in, const int* in_sizes, int n_in,
                              void* d_out, int out_size, void* d_ws, size_t ws_size,
                              hipStream_t stream)
{
    const float* x      = (const float*)d_in[0];
    const float* Wq     = (const float*)d_in[1];
    const float* bq     = (const float*)d_in[2];
    const float* Wk     = (const float*)d_in[3];
    const float* bk     = (const float*)d_in[4];
    const float* Wv     = (const float*)d_in[5];
    const float* bv     = (const float*)d_in[6];
    const float* Wo     = (const float*)d_in[7];
    const float* bo     = (const float*)d_in[8];
    const float* alpha1 = (const float*)d_in[9];
    const float* beta1  = (const float*)d_in[10];
    const float* alpha2 = (const float*)d_in[11];
    const float* beta2  = (const float*)d_in[12];
    const float* W1     = (const float*)d_in[13];
    const float* b1     = (const float*)d_in[14];
    const float* W2     = (const float*)d_in[15];
    const float* b2     = (const float*)d_in[16];

    char* ws = (char*)d_ws;
    const size_t MB = 1ull << 20;
    bf16*  Wqkv_t = (bf16*)(ws + 0 * MB);    // 6 MB
    bf16*  Wo_t   = (bf16*)(ws + 6 * MB);    // 2 MB
    bf16*  W1_t   = (bf16*)(ws + 8 * MB);    // 1 MB
    bf16*  W2_t   = (bf16*)(ws + 9 * MB);    // 1 MB
    float* b_qkv  = (float*)(ws + 10 * MB);
    bf16*  xn     = (bf16*)(ws + 11 * MB);   // 8 MB (live until Wo epilogue)
    bf16*  qkv    = (bf16*)(ws + 19 * MB);   // 24 MB (q,k live until attn)
    bf16*  vT     = (bf16*)(ws + 43 * MB);   // 8 MB (dead after attn)
    bf16*  o      = (bf16*)(ws + 51 * MB);   // 8 MB (dead after Wo)
    float* x2     = (float*)(ws + 19 * MB);  // fp32 16 MB over dead qkv head
    bf16*  hn     = (bf16*)(ws + 35 * MB);   // 8 MB over dead qkv tail
    float* pF1    = (float*)(ws + 43 * MB);  // 2x8 MB partials over dead vT+o
    bf16*  h1     = (bf16*)(ws + 11 * MB);   // 4 MB over dead xn

    const int M = NB * SEQ;

    prep_norm_kernel<<<4096 + 1292, 256, 0, stream>>>(
        x, alpha1, beta1, xn, Wq, Wk, Wv, Wo, W1, W2, bq, bk, bv,
        Wqkv_t, Wo_t, W1_t, W2_t, b_qkv);

    // fused QKV GEMM, KU=2, V written transposed (KU=4 would cut occupancy 3->2)
    gemm128<bf16, 128, 2, true, false><<<dim3(24, 32), 256, 0, stream>>>(
        xn, Wqkv_t, b_qkv, nullptr, nullptr, qkv, vT, M, 3072, D_MODEL, D_MODEL, 0);

    attn_kernel<<<dim3(SEQ / 128, 32), 512, 0, stream>>>(qkv, vT, o);

    // x2 = xn + o @ Wo + bo  (BN=64, KU=4: 8 barrier iters, 512 blocks = 2/CU)
    gemm128<float, 64, 4, false, false><<<dim3(16, 32), 256, 0, stream>>>(
        o, Wo_t, bo, xn, nullptr, x2, nullptr, M, D_MODEL, D_MODEL, D_MODEL, 0);

    norm_kernel<<<M, 256, 0, stream>>>(x2, alpha2, beta2, hn);

    // FFN1 split-K (2), KU=4: fp32 partials (512 blocks = 2/CU, 4 iters each)
    gemm128<float, 64, 4, false, true><<<dim3(8, 32, 2), 256, 0, stream>>>(
        hn, W1_t, nullptr, nullptr, nullptr, pF1, nullptr, M, 512, D_MODEL, D_MODEL, 0);

    // combine + ReLU -> h1 (bf16)
    crelu_kernel<<<(M * 512) / 1024, 256, 0, stream>>>(
        pF1, pF1 + (size_t)M * 512, b1, h1);

    // out = x2 + h1 @ W2 + b2  (BN=64, KU=4: 4 barrier iters, 512 blocks)
    gemm128<float, 64, 4, false, false><<<dim3(16, 32), 256, 0, stream>>>(
        h1, W2_t, b2, nullptr, x2, (float*)d_out, nullptr, M, D_MODEL, 512, 512, 0);
}